// Round 23
// baseline (193.950 us; speedup 1.0000x reference)
//
#include <hip/hip_runtime.h>
#include <hip/hip_bf16.h>
#include <cstdint>
#include <cstddef>

// ---------- constants ----------
#define BATCH 2
#define CTX 2048
#define EMB 2048
#define NH 16
#define NG 4
#define HD 128
#define NQK (EMB + 2*NG*HD)   // 3072 combined QKV output cols
#define MROWS (BATCH*CTX)     // 4096

typedef __bf16 bf16x8 __attribute__((ext_vector_type(8)));
typedef float  f32x4  __attribute__((ext_vector_type(4)));
typedef float  f32x16 __attribute__((ext_vector_type(16)));

__device__ __forceinline__ ushort f2bf(float f) {
    uint32_t u = __float_as_uint(f);
    u += 0x7FFFu + ((u >> 16) & 1u);   // round-to-nearest-even
    return (ushort)(u >> 16);
}

__device__ __forceinline__ float bf2f(ushort u) {
    return __uint_as_float((uint32_t)u << 16);
}

__device__ __forceinline__ uint32_t packbf(float a, float b) {
    ushort lo = __builtin_bit_cast(ushort, (__bf16)a);
    ushort hi = __builtin_bit_cast(ushort, (__bf16)b);
    return (uint32_t)lo | ((uint32_t)hi << 16);
}

__device__ __forceinline__ bf16x8 mkfrag(uint32_t a, uint32_t b, uint32_t c, uint32_t d) {
    union { uint32_t u[4]; bf16x8 v; } z;
    z.u[0] = a; z.u[1] = b; z.u[2] = c; z.u[3] = d;
    return z.v;
}

__device__ __forceinline__ void gload_lds16(const void* g, void* l) {
    __builtin_amdgcn_global_load_lds((const __attribute__((address_space(1))) void*)g,
                                     (__attribute__((address_space(3))) void*)l, 16, 0, 0);
}

// ---------- fused prep: sintab + x->bf16 + all 4 weight transposes (one launch) ----------
#define PREP_SIN 512
#define PREP_CVT 4096
__global__ __launch_bounds__(256) void k_prep(const float* __restrict__ x,
                                              const float* __restrict__ Wq, const float* __restrict__ Wk,
                                              const float* __restrict__ Wv, const float* __restrict__ Wo,
                                              float* __restrict__ sintab, ushort* __restrict__ xb,
                                              ushort* __restrict__ Wt, ushort* __restrict__ Wot) {
    int B = blockIdx.x;
    int tid = threadIdx.x;
    if (B < PREP_SIN) {
        int t = B * 256 + tid;   // 2048*64
        int j = t & 63, p = t >> 6;
        float theta = 1.0f / powf(10000.0f, (float)(2 * j) / 64.0f);
        sintab[t] = sinf((float)p * theta);
        return;
    }
    if (B < PREP_SIN + PREP_CVT) {
        int i = (B - PREP_SIN) * 256 + tid;
        const float4* src = (const float4*)x;
        ushort4* dst = (ushort4*)xb;
        #pragma unroll
        for (int k = 0; k < 2; ++k) {
            float4 v = src[i*2 + k];
            ushort4 o;
            o.x = f2bf(v.x); o.y = f2bf(v.y); o.z = f2bf(v.z); o.w = f2bf(v.w);
            dst[i*2 + k] = o;
        }
        return;
    }
    // transposes
    __shared__ float tile[32][33];
    int zz = B - (PREP_SIN + PREP_CVT);
    int z = zz >> 12;                // /4096
    int rem = zz & 4095;
    int bxx = rem & 63, byy = rem >> 6;
    const float* src; ushort* dst; int src_ld, ncols;
    if (z == 0)      { src = Wq; dst = Wt;                               src_ld = EMB;   ncols = EMB; }
    else if (z == 1) { src = Wk; dst = Wt + (size_t)EMB * EMB;           src_ld = NG*HD; ncols = NG*HD; }
    else if (z == 2) { src = Wv; dst = Wt + (size_t)(EMB + NG*HD) * EMB; src_ld = NG*HD; ncols = NG*HD; }
    else             { src = Wo; dst = Wot;                              src_ld = EMB;   ncols = EMB; }
    int c0 = bxx * 32, r0 = byy * 32;
    if (c0 >= ncols) return;
    int tx = tid & 31, ty = tid >> 5;            // 32 x 8
    #pragma unroll
    for (int i = 0; i < 4; ++i)
        tile[ty + i*8][tx] = src[(size_t)(r0 + ty + i*8) * src_ld + c0 + tx];
    __syncthreads();
    #pragma unroll
    for (int i = 0; i < 4; ++i)
        dst[(size_t)(c0 + ty + i*8) * EMB + r0 + tx] = f2bf(tile[tx][ty + i*8]);
}

// ---------- QKV GEMM with FUSED RoPE + fragment-order epilogue ----------
#define CLDS_STRIDE 130
__global__ __launch_bounds__(256) void k_gemm_qkv(const ushort* __restrict__ A, const ushort* __restrict__ Bt,
                                                  const float* __restrict__ sintab,
                                                  ushort* __restrict__ Qf, ushort* __restrict__ Kf,
                                                  ushort* __restrict__ Vf, float qscale) {
    __shared__ __align__(16) char smem[33792];   // staging: A 2x8KB @0, B 2x8KB @16384; epilogue: [128][130] ushort
    int tid = threadIdx.x;
    int lane = tid & 63;
    int wave = tid >> 6;
    int wr = wave >> 1, wc = wave & 1;

    // XCD-bijective swizzle of flattened block id (round-17 proven form)
    int nbx = gridDim.x;                       // 24
    int id  = blockIdx.y * nbx + blockIdx.x;
    int cpx = (nbx * gridDim.y) >> 3;
    int sid = (id & 7) * cpx + (id >> 3);
    int bx = sid % nbx, by = sid / nbx;
    int m0 = by * 128, n0 = bx * 128;

    int lr = lane & 15, lg = lane >> 4;

    f32x4 acc[4][4] = {};

    int arow = lane >> 2;        // 0..15 within chunk
    int kpart = (lane & 3) * 8;  // 0,8,16,24

    ushort* As = (ushort*)smem;            // [2][4096]
    ushort* Bs = (ushort*)(smem + 16384);  // [2][4096]

    int c0s = (wave*2 + 0) * 512, c1s = (wave*2 + 1) * 512;
    const ushort* ga0 = A  + (size_t)(m0 + (wave*2+0)*16 + arow) * EMB + kpart;
    const ushort* ga1 = A  + (size_t)(m0 + (wave*2+1)*16 + arow) * EMB + kpart;
    const ushort* gb0 = Bt + (size_t)(n0 + (wave*2+0)*16 + arow) * EMB + kpart;
    const ushort* gb1 = Bt + (size_t)(n0 + (wave*2+1)*16 + arow) * EMB + kpart;

    auto stage = [&](int koff, int bufoff) {
        gload_lds16(ga0 + koff, &As[bufoff + c0s]);
        gload_lds16(ga1 + koff, &As[bufoff + c1s]);
        gload_lds16(gb0 + koff, &Bs[bufoff + c0s]);
        gload_lds16(gb1 + koff, &Bs[bufoff + c1s]);
    };
    auto compute = [&](int bufoff) {
        bf16x8 af[4], bfr[4];
        #pragma unroll
        for (int mt = 0; mt < 4; ++mt)
            af[mt] = *(const bf16x8*)&As[bufoff + (wr*64 + mt*16 + lr) * 32 + lg * 8];
        #pragma unroll
        for (int nt = 0; nt < 4; ++nt)
            bfr[nt] = *(const bf16x8*)&Bs[bufoff + (wc*64 + nt*16 + lr) * 32 + lg * 8];
        #pragma unroll
        for (int mt = 0; mt < 4; ++mt)
            #pragma unroll
            for (int nt = 0; nt < 4; ++nt)
                acc[mt][nt] = __builtin_amdgcn_mfma_f32_16x16x32_bf16(af[mt], bfr[nt], acc[mt][nt], 0, 0, 0);
    };

    const int nsteps = EMB / 32;   // 64 (even)
    stage(0, 0);
    __syncthreads();
    for (int t = 0; t + 2 < nsteps; t += 2) {
        stage(32, 4096);           // tile t+1 -> buf1
        compute(0);                // tile t
        __syncthreads();
        stage(64, 0);              // tile t+2 -> buf0
        compute(4096);             // tile t+1
        __syncthreads();
        ga0 += 64; ga1 += 64; gb0 += 64; gb1 += 64;
    }
    stage(32, 4096);               // tile nsteps-1 -> buf1
    compute(0);                    // tile nsteps-2
    __syncthreads();
    compute(4096);                 // tile nsteps-1
    __syncthreads();               // before epilogue LDS overlay

    // ---- stage C tile to LDS, col-major [col][CLDS_STRIDE] bf16 (2x ushort2 per frag) ----
    ushort* clds = (ushort*)smem;
    #pragma unroll
    for (int mt = 0; mt < 4; ++mt) {
        #pragma unroll
        for (int nt = 0; nt < 4; ++nt) {
            int col = wc*64 + nt*16 + lr;
            int row = wr*64 + mt*16 + lg*4;
            ushort2 p01, p23;
            p01.x = f2bf(acc[mt][nt][0]); p01.y = f2bf(acc[mt][nt][1]);
            p23.x = f2bf(acc[mt][nt][2]); p23.y = f2bf(acc[mt][nt][3]);
            *(ushort2*)&clds[col*CLDS_STRIDE + row]     = p01;
            *(ushort2*)&clds[col*CLDS_STRIDE + row + 2] = p23;
        }
    }
    __syncthreads();

    int xt = bx;                  // 0..23 = head selector
    int b = m0 >> 11;             // batch
    int pos0 = m0 & 2047;         // base position within batch

    if (xt < 20) {
        // RoPE (Q or K) -> fragment order
        int j = tid & 63;
        int rgrp = tid >> 6;
        ushort* dstb;
        float scl;
        if (xt < 16) { dstb = Qf + (size_t)((b*NH + xt) * 64) * 4096;      scl = qscale; }
        else         { dstb = Kf + (size_t)((b*NG + (xt-16)) * 64) * 4096; scl = 1.0f;   }
        #pragma unroll 4
        for (int it = 0; it < 32; ++it) {
            int row = rgrp + it*4;                 // 0..127
            int pos = pos0 + row;
            float a  = bf2f(clds[j*CLDS_STRIDE + row]);
            float bb = bf2f(clds[(j+64)*CLDS_STRIDE + row]);
            float sv = sintab[pos*64 + j] * scl;
            size_t idx = (size_t)(pos>>5)*4096 + (size_t)(j>>4)*512 + ((j>>3)&1)*256 + (pos&31)*8 + (j&7);
            dstb[idx]        = f2bf((a - bb) * sv);
            dstb[idx + 2048] = f2bf((bb + a) * sv);   // d=j+64 -> s+4 -> +4*512
        }
    } else {
        // V -> fragment order: Vf[((bg*64+step)*8 + dt*2+ks)*512 + lane*8 + e]
        int g = xt - 20;
        int bg = b*NG + g;
        int ln2 = tid & 31, hi2 = (tid >> 5) & 1, dt = tid >> 6;
        int colc = dt*32 + ln2;
        #pragma unroll
        for (int stp = 0; stp < 4; ++stp) {
            #pragma unroll
            for (int ks = 0; ks < 2; ++ks) {
                int rowb = stp*32 + ks*16 + hi2*8;
                union { ushort2 q[4]; bf16x8 v; } z;
                z.q[0] = *(ushort2*)&clds[colc*CLDS_STRIDE + rowb];
                z.q[1] = *(ushort2*)&clds[colc*CLDS_STRIDE + rowb + 2];
                z.q[2] = *(ushort2*)&clds[colc*CLDS_STRIDE + rowb + 4];
                z.q[3] = *(ushort2*)&clds[colc*CLDS_STRIDE + rowb + 6];
                int step_g = (pos0 >> 5) + stp;
                *(bf16x8*)(Vf + ((size_t)(bg*64 + step_g)*8 + dt*2 + ks) * 512 + (tid & 63) * 8) = z.v;
            }
        }
    }
}

// ---------- GEMM (f32 out + bias): unroll x2, pointer bump, peel, round-17 XCD swizzle ----------
__global__ __launch_bounds__(256) void k_gemm_bt(const ushort* __restrict__ A, const ushort* __restrict__ Bt,
                                                 float* __restrict__ C, int M, int N, int K,
                                                 const float* __restrict__ bias) {
    __shared__ __align__(16) ushort As[2][128 * 32];
    __shared__ __align__(16) ushort Bs[2][128 * 32];
    int tid = threadIdx.x;
    int lane = tid & 63;
    int wave = tid >> 6;
    int wr = wave >> 1, wc = wave & 1;

    // XCD-bijective swizzle (round-17 proven form)
    int nbx = gridDim.x;
    int id  = blockIdx.y * nbx + blockIdx.x;
    int cpx = (nbx * gridDim.y) >> 3;
    int sid = (id & 7) * cpx + (id >> 3);
    int bx = sid % nbx, by = sid / nbx;
    int m0 = by * 128, n0 = bx * 128;

    int lr = lane & 15, lg = lane >> 4;

    f32x4 acc[4][4] = {};

    int arow = lane >> 2;
    int kpart = (lane & 3) * 8;

    int c0s = (wave*2 + 0) * 512, c1s = (wave*2 + 1) * 512;
    const ushort* ga0 = A  + (size_t)(m0 + (wave*2+0)*16 + arow) * K + kpart;
    const ushort* ga1 = A  + (size_t)(m0 + (wave*2+1)*16 + arow) * K + kpart;
    const ushort* gb0 = Bt + (size_t)(n0 + (wave*2+0)*16 + arow) * K + kpart;
    const ushort* gb1 = Bt + (size_t)(n0 + (wave*2+1)*16 + arow) * K + kpart;

    auto stage = [&](int koff, int buf) {
        gload_lds16(ga0 + koff, &As[buf][c0s]);
        gload_lds16(ga1 + koff, &As[buf][c1s]);
        gload_lds16(gb0 + koff, &Bs[buf][c0s]);
        gload_lds16(gb1 + koff, &Bs[buf][c1s]);
    };
    auto compute = [&](int buf) {
        bf16x8 af[4], bfr[4];
        #pragma unroll
        for (int mt = 0; mt < 4; ++mt)
            af[mt] = *(const bf16x8*)&As[buf][(wr*64 + mt*16 + lr) * 32 + lg * 8];
        #pragma unroll
        for (int nt = 0; nt < 4; ++nt)
            bfr[nt] = *(const bf16x8*)&Bs[buf][(wc*64 + nt*16 + lr) * 32 + lg * 8];
        #pragma unroll
        for (int mt = 0; mt < 4; ++mt)
            #pragma unroll
            for (int nt = 0; nt < 4; ++nt)
                acc[mt][nt] = __builtin_amdgcn_mfma_f32_16x16x32_bf16(af[mt], bfr[nt], acc[mt][nt], 0, 0, 0);
    };

    int nsteps = K >> 5;           // even (64)
    stage(0, 0);
    __syncthreads();
    for (int t = 0; t + 2 < nsteps; t += 2) {
        stage(32, 1);
        compute(0);
        __syncthreads();
        stage(64, 0);
        compute(1);
        __syncthreads();
        ga0 += 64; ga1 += 64; gb0 += 64; gb1 += 64;
    }
    stage(32, 1);
    compute(0);
    __syncthreads();
    compute(1);

    #pragma unroll
    for (int mt = 0; mt < 4; ++mt) {
        #pragma unroll
        for (int nt = 0; nt < 4; ++nt) {
            int col = n0 + wc*64 + nt*16 + lr;
            float bv = bias ? bias[col] : 0.0f;
            #pragma unroll
            for (int r = 0; r < 4; ++r) {
                int row = m0 + wr*64 + mt*16 + lg*4 + r;
                C[(size_t)row * N + col] = acc[mt][nt][r] + bv;
            }
        }
    }
}

// ---------- flash attention v16: v15 + counted vmcnt (no full drain in the round loop) ----------
// Round r: step(r, buf[r&1]) -> s_barrier (all reads done) -> stage(r+2 -> buf[r&1]) ->
// s_waitcnt vmcnt(4) (waits ONLY stage(r+1); stage(r+2)'s 4 loads stay in flight) -> s_barrier
// (all waves' stage(r+1) data in LDS). Each wave issues exactly 4 gload_lds per stageKV.
__global__ __launch_bounds__(512) void k_attn16(const ushort* __restrict__ Qf, const ushort* __restrict__ Kf,
                                                const ushort* __restrict__ Vf, ushort* __restrict__ y) {
    __shared__ __align__(16) char smem[66048];
    // loop: KV buf0 @0 (K 2x8KB @0, V 2x8KB @16384), KV buf1 @32768 (same layout)
    // merge overlay: head hh -> sOd f32[32][128] @hh*16512, sl f32[32] @hh*16512+16384

    int tid  = threadIdx.x;
    int lane = tid & 63;
    int w    = tid >> 6;           // 0..7
    int hh   = w >> 1, ww = w & 1; // head-within-group, split-KV wave
    int B  = blockIdx.x;
    int bg = B & 7;                // XCD-local K/V set
    int t  = 63 - (B >> 3);        // q-tile index, longest first within XCD
    int b = bg >> 2, g = bg & 3, h = g * 4 + hh;
    int ln = lane & 31, hi = lane >> 5;
    int q0 = t * 32;

    const ushort* kf_g = Kf + (size_t)bg * 64 * 4096;
    const ushort* vf_g = Vf + (size_t)bg * 64 * 4096;

    auto stageKV = [&](int r, int bufoff) {   // 4 gload_lds per thread (16KB K + 16KB V total)
        #pragma unroll
        for (int s2 = 0; s2 < 2; ++s2) {
            gload_lds16(kf_g + r*8192 + s2*4096 + tid*8, smem + bufoff + s2*8192 + tid*16);
            gload_lds16(vf_g + r*8192 + s2*4096 + tid*8, smem + bufoff + 16384 + s2*8192 + tid*16);
        }
    };

    // Q tile in registers (fragment order: contiguous 1KB per s, coalesced across lanes)
    bf16x8 qf[8];
    {
        const ushort* qsrc = Qf + ((size_t)((b*NH + h) * 64 + t)) * 4096 + lane * 8;
        #pragma unroll
        for (int s = 0; s < 8; ++s) qf[s] = *(const bf16x8*)(qsrc + s * 512);
    }

    int rounds = (t >> 1) + 1;     // key-tile pairs covering tiles 0..t

    // prologue: stage rounds 0 (+1 if present); wait only round 0 before starting
    stageKV(0, 0);
    if (rounds > 1) {
        stageKV(1, 32768);
        asm volatile("s_waitcnt vmcnt(4)" ::: "memory");
    } else {
        asm volatile("s_waitcnt vmcnt(0)" ::: "memory");
    }
    __builtin_amdgcn_s_barrier();

    f32x16 od[4] = {};             // O: row q = (r&3)+8*(r>>2)+4*hi, col d = dt*32+ln
    float lsum = 0.0f;             // own half's kv rows only (cross-half added post-loop)

    auto step = [&](int bufoff, bool diag) {
        const char* ksl = smem + bufoff + ww*8192 + lane*16;
        const char* vsl = smem + bufoff + 16384 + ww*8192 + lane*16;
        f32x16 st = {};
        #pragma unroll
        for (int s = 0; s < 8; ++s) {
            bf16x8 kf = *(const bf16x8*)(ksl + s * 1024);
            st = __builtin_amdgcn_mfma_f32_32x32x16_bf16(kf, qf[s], st, 0, 0, 0);
        }
        if (diag) {
            #pragma unroll
            for (int r = 0; r < 16; ++r) {
                int kl = (r & 3) + 8*(r >> 2) + 4*hi;
                if (kl > ln) st[r] = -1e30f;
            }
        }
        // P = exp2(S) (exact; masked -> 0); own-half pairwise-tree row sum
        #pragma unroll
        for (int r = 0; r < 16; ++r) st[r] = exp2f(st[r]);
        float s8[8];
        #pragma unroll
        for (int r = 0; r < 8; ++r) s8[r] = st[r] + st[r+8];
        #pragma unroll
        for (int r = 0; r < 4; ++r) s8[r] = s8[r] + s8[r+4];
        lsum += (s8[0] + s8[1]) + (s8[2] + s8[3]);

        // O += P.V; 2 shfls per ks-half
        #pragma unroll
        for (int ks = 0; ks < 2; ++ks) {
            uint32_t w0 = packbf(st[8*ks+0], st[8*ks+1]);
            uint32_t w1 = packbf(st[8*ks+2], st[8*ks+3]);
            uint32_t w2 = packbf(st[8*ks+4], st[8*ks+5]);
            uint32_t w3 = packbf(st[8*ks+6], st[8*ks+7]);
            uint32_t sa = hi ? w0 : w2;
            uint32_t sb = hi ? w1 : w3;
            uint32_t ra = (uint32_t)__shfl_xor((int)sa, 32, 64);
            uint32_t rb = (uint32_t)__shfl_xor((int)sb, 32, 64);
            bf16x8 pa = hi ? mkfrag(ra, rb, w2, w3) : mkfrag(w0, w1, ra, rb);
            #pragma unroll
            for (int dt = 0; dt < 4; ++dt) {
                bf16x8 vf = *(const bf16x8*)(vsl + (dt*2 + ks) * 1024);
                od[dt] = __builtin_amdgcn_mfma_f32_32x32x16_bf16(pa, vf, od[dt], 0, 0, 0);
            }
        }
    };

    for (int r = 0; r < rounds; ++r) {
        int tile = 2*r + ww;
        if (tile <= t) step((r & 1) ? 32768 : 0, tile == t);
        __builtin_amdgcn_s_barrier();              // all reads of buf[r&1] done
        if (r + 2 < rounds) {
            stageKV(r + 2, (r & 1) ? 32768 : 0);   // overwrite buf[r&1] (= buf[(r+2)&1])
            asm volatile("s_waitcnt vmcnt(4)" ::: "memory");   // stage(r+1) landed
        } else {
            asm volatile("s_waitcnt vmcnt(0)" ::: "memory");   // drain tail stages
        }
        __builtin_amdgcn_s_barrier();              // all waves' stage(r+1) visible
    }

    // complete lsum across lane halves
    lsum += __shfl_xor(lsum, 32, 64);

    // ---- per-head merge (overlay on KV LDS; final loop barrier already passed) ----
    float* sOd = (float*)(smem + hh*16512);
    float* sl  = (float*)(smem + hh*16512 + 16384);
    if (ww == 1) {
        #pragma unroll
        for (int r = 0; r < 16; ++r) {
            int ri = (r & 3) + 8*(r >> 2) + 4*hi;
            #pragma unroll
            for (int dt = 0; dt < 4; ++dt) sOd[ri*128 + dt*32 + ln] = od[dt][r];
        }
        if (hi == 0) sl[ln] = lsum;
    }
    __syncthreads();
    if (ww == 0) {
        float inv = 1.0f / (lsum + sl[ln]);
        #pragma unroll
        for (int r = 0; r < 16; ++r) {
            int ri = (r & 3) + 8*(r >> 2) + 4*hi;
            float ivr = __shfl(inv, ri, 64);
            int row = q0 + ri;
            #pragma unroll
            for (int dt = 0; dt < 4; ++dt) {
                float v = (od[dt][r] + sOd[ri*128 + dt*32 + ln]) * ivr;
                y[((size_t)(b*CTX + row)) * (NH*HD) + h*HD + dt*32 + ln] = f2bf(v);
            }
        }
    }
}

// ---------- workspace layout (bytes) ----------
#define SIN_OFF   ((size_t)0)
#define XB_OFF    ((size_t)524288)
#define WT_OFF    ((size_t)17301504)
#define WOT_OFF   ((size_t)29884416)
#define QB_OFF    ((size_t)88604672)
#define KB_OFF    ((size_t)105381888)
#define VT_OFF    ((size_t)109576192)
#define YB_OFF    ((size_t)113770496)

extern "C" void kernel_launch(void* const* d_in, const int* in_sizes, int n_in,
                              void* d_out, int out_size, void* d_ws, size_t ws_size,
                              hipStream_t stream) {
    const float* x  = (const float*)d_in[0];
    const float* Wq = (const float*)d_in[1];
    const float* Wk = (const float*)d_in[2];
    const float* Wv = (const float*)d_in[3];
    const float* Wo = (const float*)d_in[4];
    const float* bo = (const float*)d_in[5];
    float* out = (float*)d_out;
    char* ws = (char*)d_ws;

    float*  sintab = (float*)(ws + SIN_OFF);
    ushort* xb     = (ushort*)(ws + XB_OFF);
    ushort* Wt     = (ushort*)(ws + WT_OFF);
    ushort* Wot    = (ushort*)(ws + WOT_OFF);
    ushort* Qf     = (ushort*)(ws + QB_OFF);
    ushort* Kf     = (ushort*)(ws + KB_OFF);
    ushort* Vf     = (ushort*)(ws + VT_OFF);
    ushort* yb     = (ushort*)(ws + YB_OFF);

    const float qscale = 0.08838834764831845f * 1.4426950408889634f;  // 1/sqrt(128) * log2(e)

    // 1. fused prep: sintab + x->bf16 + weight transposes
    k_prep<<<PREP_SIN + PREP_CVT + 4*4096, 256, 0, stream>>>(x, Wq, Wk, Wv, Wo, sintab, xb, Wt, Wot);
    // 2. QKV GEMM with fused RoPE + fragment-order epilogue -> Qf, Kf, Vf directly
    k_gemm_qkv<<<dim3(NQK/128, MROWS/128), 256, 0, stream>>>(xb, Wt, sintab, Qf, Kf, Vf, qscale);
    // 3. attention (512 blocks x 8 waves, Q in regs, KV double-buffered, counted vmcnt)
    k_attn16<<<512, 512, 0, stream>>>(Qf, Kf, Vf, yb);
    // 4. out = y @ Wo + bo  (f32 out)
    k_gemm_bt<<<dim3(EMB/128, MROWS/128), 256, 0, stream>>>(yb, Wot, out, MROWS, EMB, EMB, bo);
}

// Round 24
// 190.422 us; speedup vs baseline: 1.0185x; 1.0185x over previous
//
#include <hip/hip_runtime.h>
#include <hip/hip_bf16.h>
#include <cstdint>
#include <cstddef>

// ---------- constants ----------
#define BATCH 2
#define CTX 2048
#define EMB 2048
#define NH 16
#define NG 4
#define HD 128
#define NQK (EMB + 2*NG*HD)   // 3072 combined QKV output cols
#define MROWS (BATCH*CTX)     // 4096

typedef __bf16 bf16x8 __attribute__((ext_vector_type(8)));
typedef float  f32x4  __attribute__((ext_vector_type(4)));
typedef float  f32x16 __attribute__((ext_vector_type(16)));

__device__ __forceinline__ ushort f2bf(float f) {
    uint32_t u = __float_as_uint(f);
    u += 0x7FFFu + ((u >> 16) & 1u);   // round-to-nearest-even
    return (ushort)(u >> 16);
}

__device__ __forceinline__ float bf2f(ushort u) {
    return __uint_as_float((uint32_t)u << 16);
}

__device__ __forceinline__ uint32_t packbf(float a, float b) {
    ushort lo = __builtin_bit_cast(ushort, (__bf16)a);
    ushort hi = __builtin_bit_cast(ushort, (__bf16)b);
    return (uint32_t)lo | ((uint32_t)hi << 16);
}

__device__ __forceinline__ bf16x8 mkfrag(uint32_t a, uint32_t b, uint32_t c, uint32_t d) {
    union { uint32_t u[4]; bf16x8 v; } z;
    z.u[0] = a; z.u[1] = b; z.u[2] = c; z.u[3] = d;
    return z.v;
}

__device__ __forceinline__ void gload_lds16(const void* g, void* l) {
    __builtin_amdgcn_global_load_lds((const __attribute__((address_space(1))) void*)g,
                                     (__attribute__((address_space(3))) void*)l, 16, 0, 0);
}

// ---------- fused prep: sintab + x->bf16 + all 4 weight transposes (one launch) ----------
#define PREP_SIN 512
#define PREP_CVT 4096
__global__ __launch_bounds__(256) void k_prep(const float* __restrict__ x,
                                              const float* __restrict__ Wq, const float* __restrict__ Wk,
                                              const float* __restrict__ Wv, const float* __restrict__ Wo,
                                              float* __restrict__ sintab, ushort* __restrict__ xb,
                                              ushort* __restrict__ Wt, ushort* __restrict__ Wot) {
    int B = blockIdx.x;
    int tid = threadIdx.x;
    if (B < PREP_SIN) {
        int t = B * 256 + tid;   // 2048*64
        int j = t & 63, p = t >> 6;
        float theta = 1.0f / powf(10000.0f, (float)(2 * j) / 64.0f);
        sintab[t] = sinf((float)p * theta);
        return;
    }
    if (B < PREP_SIN + PREP_CVT) {
        int i = (B - PREP_SIN) * 256 + tid;
        const float4* src = (const float4*)x;
        ushort4* dst = (ushort4*)xb;
        #pragma unroll
        for (int k = 0; k < 2; ++k) {
            float4 v = src[i*2 + k];
            ushort4 o;
            o.x = f2bf(v.x); o.y = f2bf(v.y); o.z = f2bf(v.z); o.w = f2bf(v.w);
            dst[i*2 + k] = o;
        }
        return;
    }
    // transposes
    __shared__ float tile[32][33];
    int zz = B - (PREP_SIN + PREP_CVT);
    int z = zz >> 12;                // /4096
    int rem = zz & 4095;
    int bxx = rem & 63, byy = rem >> 6;
    const float* src; ushort* dst; int src_ld, ncols;
    if (z == 0)      { src = Wq; dst = Wt;                               src_ld = EMB;   ncols = EMB; }
    else if (z == 1) { src = Wk; dst = Wt + (size_t)EMB * EMB;           src_ld = NG*HD; ncols = NG*HD; }
    else if (z == 2) { src = Wv; dst = Wt + (size_t)(EMB + NG*HD) * EMB; src_ld = NG*HD; ncols = NG*HD; }
    else             { src = Wo; dst = Wot;                              src_ld = EMB;   ncols = EMB; }
    int c0 = bxx * 32, r0 = byy * 32;
    if (c0 >= ncols) return;
    int tx = tid & 31, ty = tid >> 5;            // 32 x 8
    #pragma unroll
    for (int i = 0; i < 4; ++i)
        tile[ty + i*8][tx] = src[(size_t)(r0 + ty + i*8) * src_ld + c0 + tx];
    __syncthreads();
    #pragma unroll
    for (int i = 0; i < 4; ++i)
        dst[(size_t)(c0 + ty + i*8) * EMB + r0 + tx] = f2bf(tile[tx][ty + i*8]);
}

// ---------- QKV GEMM with FUSED RoPE + fragment-order epilogue ----------
#define CLDS_STRIDE 130
__global__ __launch_bounds__(256) void k_gemm_qkv(const ushort* __restrict__ A, const ushort* __restrict__ Bt,
                                                  const float* __restrict__ sintab,
                                                  ushort* __restrict__ Qf, ushort* __restrict__ Kf,
                                                  ushort* __restrict__ Vf, float qscale) {
    __shared__ __align__(16) char smem[33792];   // staging: A 2x8KB @0, B 2x8KB @16384; epilogue: [128][130] ushort
    int tid = threadIdx.x;
    int lane = tid & 63;
    int wave = tid >> 6;
    int wr = wave >> 1, wc = wave & 1;

    // XCD-bijective swizzle of flattened block id (round-17 proven form)
    int nbx = gridDim.x;                       // 24
    int id  = blockIdx.y * nbx + blockIdx.x;
    int cpx = (nbx * gridDim.y) >> 3;
    int sid = (id & 7) * cpx + (id >> 3);
    int bx = sid % nbx, by = sid / nbx;
    int m0 = by * 128, n0 = bx * 128;

    int lr = lane & 15, lg = lane >> 4;

    f32x4 acc[4][4] = {};

    int arow = lane >> 2;        // 0..15 within chunk
    int kpart = (lane & 3) * 8;  // 0,8,16,24

    ushort* As = (ushort*)smem;            // [2][4096]
    ushort* Bs = (ushort*)(smem + 16384);  // [2][4096]

    int c0s = (wave*2 + 0) * 512, c1s = (wave*2 + 1) * 512;
    const ushort* ga0 = A  + (size_t)(m0 + (wave*2+0)*16 + arow) * EMB + kpart;
    const ushort* ga1 = A  + (size_t)(m0 + (wave*2+1)*16 + arow) * EMB + kpart;
    const ushort* gb0 = Bt + (size_t)(n0 + (wave*2+0)*16 + arow) * EMB + kpart;
    const ushort* gb1 = Bt + (size_t)(n0 + (wave*2+1)*16 + arow) * EMB + kpart;

    auto stage = [&](int koff, int bufoff) {
        gload_lds16(ga0 + koff, &As[bufoff + c0s]);
        gload_lds16(ga1 + koff, &As[bufoff + c1s]);
        gload_lds16(gb0 + koff, &Bs[bufoff + c0s]);
        gload_lds16(gb1 + koff, &Bs[bufoff + c1s]);
    };
    auto compute = [&](int bufoff) {
        bf16x8 af[4], bfr[4];
        #pragma unroll
        for (int mt = 0; mt < 4; ++mt)
            af[mt] = *(const bf16x8*)&As[bufoff + (wr*64 + mt*16 + lr) * 32 + lg * 8];
        #pragma unroll
        for (int nt = 0; nt < 4; ++nt)
            bfr[nt] = *(const bf16x8*)&Bs[bufoff + (wc*64 + nt*16 + lr) * 32 + lg * 8];
        #pragma unroll
        for (int mt = 0; mt < 4; ++mt)
            #pragma unroll
            for (int nt = 0; nt < 4; ++nt)
                acc[mt][nt] = __builtin_amdgcn_mfma_f32_16x16x32_bf16(af[mt], bfr[nt], acc[mt][nt], 0, 0, 0);
    };

    const int nsteps = EMB / 32;   // 64 (even)
    stage(0, 0);
    __syncthreads();
    for (int t = 0; t + 2 < nsteps; t += 2) {
        stage(32, 4096);           // tile t+1 -> buf1
        compute(0);                // tile t
        __syncthreads();
        stage(64, 0);              // tile t+2 -> buf0
        compute(4096);             // tile t+1
        __syncthreads();
        ga0 += 64; ga1 += 64; gb0 += 64; gb1 += 64;
    }
    stage(32, 4096);               // tile nsteps-1 -> buf1
    compute(0);                    // tile nsteps-2
    __syncthreads();
    compute(4096);                 // tile nsteps-1
    __syncthreads();               // before epilogue LDS overlay

    // ---- stage C tile to LDS, col-major [col][CLDS_STRIDE] bf16 (2x ushort2 per frag) ----
    ushort* clds = (ushort*)smem;
    #pragma unroll
    for (int mt = 0; mt < 4; ++mt) {
        #pragma unroll
        for (int nt = 0; nt < 4; ++nt) {
            int col = wc*64 + nt*16 + lr;
            int row = wr*64 + mt*16 + lg*4;
            ushort2 p01, p23;
            p01.x = f2bf(acc[mt][nt][0]); p01.y = f2bf(acc[mt][nt][1]);
            p23.x = f2bf(acc[mt][nt][2]); p23.y = f2bf(acc[mt][nt][3]);
            *(ushort2*)&clds[col*CLDS_STRIDE + row]     = p01;
            *(ushort2*)&clds[col*CLDS_STRIDE + row + 2] = p23;
        }
    }
    __syncthreads();

    int xt = bx;                  // 0..23 = head selector
    int b = m0 >> 11;             // batch
    int pos0 = m0 & 2047;         // base position within batch

    if (xt < 20) {
        // RoPE (Q or K) -> fragment order
        int j = tid & 63;
        int rgrp = tid >> 6;
        ushort* dstb;
        float scl;
        if (xt < 16) { dstb = Qf + (size_t)((b*NH + xt) * 64) * 4096;      scl = qscale; }
        else         { dstb = Kf + (size_t)((b*NG + (xt-16)) * 64) * 4096; scl = 1.0f;   }
        #pragma unroll 4
        for (int it = 0; it < 32; ++it) {
            int row = rgrp + it*4;                 // 0..127
            int pos = pos0 + row;
            float a  = bf2f(clds[j*CLDS_STRIDE + row]);
            float bb = bf2f(clds[(j+64)*CLDS_STRIDE + row]);
            float sv = sintab[pos*64 + j] * scl;
            size_t idx = (size_t)(pos>>5)*4096 + (size_t)(j>>4)*512 + ((j>>3)&1)*256 + (pos&31)*8 + (j&7);
            dstb[idx]        = f2bf((a - bb) * sv);
            dstb[idx + 2048] = f2bf((bb + a) * sv);   // d=j+64 -> s+4 -> +4*512
        }
    } else {
        // V -> fragment order: Vf[((bg*64+step)*8 + dt*2+ks)*512 + lane*8 + e]
        int g = xt - 20;
        int bg = b*NG + g;
        int ln2 = tid & 31, hi2 = (tid >> 5) & 1, dt = tid >> 6;
        int colc = dt*32 + ln2;
        #pragma unroll
        for (int stp = 0; stp < 4; ++stp) {
            #pragma unroll
            for (int ks = 0; ks < 2; ++ks) {
                int rowb = stp*32 + ks*16 + hi2*8;
                union { ushort2 q[4]; bf16x8 v; } z;
                z.q[0] = *(ushort2*)&clds[colc*CLDS_STRIDE + rowb];
                z.q[1] = *(ushort2*)&clds[colc*CLDS_STRIDE + rowb + 2];
                z.q[2] = *(ushort2*)&clds[colc*CLDS_STRIDE + rowb + 4];
                z.q[3] = *(ushort2*)&clds[colc*CLDS_STRIDE + rowb + 6];
                int step_g = (pos0 >> 5) + stp;
                *(bf16x8*)(Vf + ((size_t)(bg*64 + step_g)*8 + dt*2 + ks) * 512 + (tid & 63) * 8) = z.v;
            }
        }
    }
}

// ---------- GEMM (f32 out + bias): unroll x2, pointer bump, peel, round-17 XCD swizzle ----------
__global__ __launch_bounds__(256) void k_gemm_bt(const ushort* __restrict__ A, const ushort* __restrict__ Bt,
                                                 float* __restrict__ C, int M, int N, int K,
                                                 const float* __restrict__ bias) {
    __shared__ __align__(16) ushort As[2][128 * 32];
    __shared__ __align__(16) ushort Bs[2][128 * 32];
    int tid = threadIdx.x;
    int lane = tid & 63;
    int wave = tid >> 6;
    int wr = wave >> 1, wc = wave & 1;

    // XCD-bijective swizzle (round-17 proven form)
    int nbx = gridDim.x;
    int id  = blockIdx.y * nbx + blockIdx.x;
    int cpx = (nbx * gridDim.y) >> 3;
    int sid = (id & 7) * cpx + (id >> 3);
    int bx = sid % nbx, by = sid / nbx;
    int m0 = by * 128, n0 = bx * 128;

    int lr = lane & 15, lg = lane >> 4;

    f32x4 acc[4][4] = {};

    int arow = lane >> 2;
    int kpart = (lane & 3) * 8;

    int c0s = (wave*2 + 0) * 512, c1s = (wave*2 + 1) * 512;
    const ushort* ga0 = A  + (size_t)(m0 + (wave*2+0)*16 + arow) * K + kpart;
    const ushort* ga1 = A  + (size_t)(m0 + (wave*2+1)*16 + arow) * K + kpart;
    const ushort* gb0 = Bt + (size_t)(n0 + (wave*2+0)*16 + arow) * K + kpart;
    const ushort* gb1 = Bt + (size_t)(n0 + (wave*2+1)*16 + arow) * K + kpart;

    auto stage = [&](int koff, int buf) {
        gload_lds16(ga0 + koff, &As[buf][c0s]);
        gload_lds16(ga1 + koff, &As[buf][c1s]);
        gload_lds16(gb0 + koff, &Bs[buf][c0s]);
        gload_lds16(gb1 + koff, &Bs[buf][c1s]);
    };
    auto compute = [&](int buf) {
        bf16x8 af[4], bfr[4];
        #pragma unroll
        for (int mt = 0; mt < 4; ++mt)
            af[mt] = *(const bf16x8*)&As[buf][(wr*64 + mt*16 + lr) * 32 + lg * 8];
        #pragma unroll
        for (int nt = 0; nt < 4; ++nt)
            bfr[nt] = *(const bf16x8*)&Bs[buf][(wc*64 + nt*16 + lr) * 32 + lg * 8];
        #pragma unroll
        for (int mt = 0; mt < 4; ++mt)
            #pragma unroll
            for (int nt = 0; nt < 4; ++nt)
                acc[mt][nt] = __builtin_amdgcn_mfma_f32_16x16x32_bf16(af[mt], bfr[nt], acc[mt][nt], 0, 0, 0);
    };

    int nsteps = K >> 5;           // even (64)
    stage(0, 0);
    __syncthreads();
    for (int t = 0; t + 2 < nsteps; t += 2) {
        stage(32, 1);
        compute(0);
        __syncthreads();
        stage(64, 0);
        compute(1);
        __syncthreads();
        ga0 += 64; ga1 += 64; gb0 += 64; gb1 += 64;
    }
    stage(32, 1);
    compute(0);
    __syncthreads();
    compute(1);

    #pragma unroll
    for (int mt = 0; mt < 4; ++mt) {
        #pragma unroll
        for (int nt = 0; nt < 4; ++nt) {
            int col = n0 + wc*64 + nt*16 + lr;
            float bv = bias ? bias[col] : 0.0f;
            #pragma unroll
            for (int r = 0; r < 4; ++r) {
                int row = m0 + wr*64 + mt*16 + lg*4 + r;
                C[(size_t)row * N + col] = acc[mt][nt][r] + bv;
            }
        }
    }
}

// ---------- flash attention v15 (round-22 best): Q in regs, KV double-buffer, 1 barrier/round ----------
__global__ __launch_bounds__(512) void k_attn15(const ushort* __restrict__ Qf, const ushort* __restrict__ Kf,
                                                const ushort* __restrict__ Vf, ushort* __restrict__ y) {
    __shared__ __align__(16) char smem[66048];
    // loop: KV buf0 @0 (K 2x8KB @0, V 2x8KB @16384), KV buf1 @32768 (same layout)
    // merge overlay: head hh -> sOd f32[32][128] @hh*16512, sl f32[32] @hh*16512+16384

    int tid  = threadIdx.x;
    int lane = tid & 63;
    int w    = tid >> 6;           // 0..7
    int hh   = w >> 1, ww = w & 1; // head-within-group, split-KV wave
    int B  = blockIdx.x;
    int bg = B & 7;                // XCD-local K/V set
    int t  = 63 - (B >> 3);        // q-tile index, longest first within XCD
    int b = bg >> 2, g = bg & 3, h = g * 4 + hh;
    int ln = lane & 31, hi = lane >> 5;
    int q0 = t * 32;

    const ushort* kf_g = Kf + (size_t)bg * 64 * 4096;
    const ushort* vf_g = Vf + (size_t)bg * 64 * 4096;

    auto stageKV = [&](int r, int bufoff) {   // stage key tiles 2r, 2r+1 (16KB K + 16KB V)
        #pragma unroll
        for (int s2 = 0; s2 < 2; ++s2) {
            gload_lds16(kf_g + r*8192 + s2*4096 + tid*8, smem + bufoff + s2*8192 + tid*16);
            gload_lds16(vf_g + r*8192 + s2*4096 + tid*8, smem + bufoff + 16384 + s2*8192 + tid*16);
        }
    };

    // Q tile in registers (fragment order: contiguous 1KB per s, coalesced across lanes)
    bf16x8 qf[8];
    {
        const ushort* qsrc = Qf + ((size_t)((b*NH + h) * 64 + t)) * 4096 + lane * 8;
        #pragma unroll
        for (int s = 0; s < 8; ++s) qf[s] = *(const bf16x8*)(qsrc + s * 512);
    }

    stageKV(0, 0);
    __syncthreads();

    f32x16 od[4] = {};             // O: row q = (r&3)+8*(r>>2)+4*hi, col d = dt*32+ln
    float lsum = 0.0f;             // own half's kv rows only (cross-half added post-loop)

    auto step = [&](int bufoff, bool diag) {
        const char* ksl = smem + bufoff + ww*8192 + lane*16;
        const char* vsl = smem + bufoff + 16384 + ww*8192 + lane*16;
        f32x16 st = {};
        #pragma unroll
        for (int s = 0; s < 8; ++s) {
            bf16x8 kf = *(const bf16x8*)(ksl + s * 1024);
            st = __builtin_amdgcn_mfma_f32_32x32x16_bf16(kf, qf[s], st, 0, 0, 0);
        }
        if (diag) {
            #pragma unroll
            for (int r = 0; r < 16; ++r) {
                int kl = (r & 3) + 8*(r >> 2) + 4*hi;
                if (kl > ln) st[r] = -1e30f;
            }
        }
        // P = exp2(S) (exact; masked -> 0); own-half pairwise-tree row sum
        #pragma unroll
        for (int r = 0; r < 16; ++r) st[r] = exp2f(st[r]);
        float s8[8];
        #pragma unroll
        for (int r = 0; r < 8; ++r) s8[r] = st[r] + st[r+8];
        #pragma unroll
        for (int r = 0; r < 4; ++r) s8[r] = s8[r] + s8[r+4];
        lsum += (s8[0] + s8[1]) + (s8[2] + s8[3]);

        // O += P.V; 2 shfls per ks-half
        #pragma unroll
        for (int ks = 0; ks < 2; ++ks) {
            uint32_t w0 = packbf(st[8*ks+0], st[8*ks+1]);
            uint32_t w1 = packbf(st[8*ks+2], st[8*ks+3]);
            uint32_t w2 = packbf(st[8*ks+4], st[8*ks+5]);
            uint32_t w3 = packbf(st[8*ks+6], st[8*ks+7]);
            uint32_t sa = hi ? w0 : w2;
            uint32_t sb = hi ? w1 : w3;
            uint32_t ra = (uint32_t)__shfl_xor((int)sa, 32, 64);
            uint32_t rb = (uint32_t)__shfl_xor((int)sb, 32, 64);
            bf16x8 pa = hi ? mkfrag(ra, rb, w2, w3) : mkfrag(w0, w1, ra, rb);
            #pragma unroll
            for (int dt = 0; dt < 4; ++dt) {
                bf16x8 vf = *(const bf16x8*)(vsl + (dt*2 + ks) * 1024);
                od[dt] = __builtin_amdgcn_mfma_f32_32x32x16_bf16(pa, vf, od[dt], 0, 0, 0);
            }
        }
    };

    int rounds = (t >> 1) + 1;     // key-tile pairs covering tiles 0..t
    for (int r = 0; r < rounds; ++r) {
        if (r + 1 < rounds) stageKV(r + 1, ((r + 1) & 1) ? 32768 : 0);
        int tile = 2*r + ww;
        if (tile <= t) step((r & 1) ? 32768 : 0, tile == t);
        __syncthreads();           // my buf reads done + next-round stage arrived (vmcnt drain)
    }

    // complete lsum across lane halves
    lsum += __shfl_xor(lsum, 32, 64);

    // ---- per-head merge (overlay on KV LDS; last loop barrier already passed) ----
    float* sOd = (float*)(smem + hh*16512);
    float* sl  = (float*)(smem + hh*16512 + 16384);
    if (ww == 1) {
        #pragma unroll
        for (int r = 0; r < 16; ++r) {
            int ri = (r & 3) + 8*(r >> 2) + 4*hi;
            #pragma unroll
            for (int dt = 0; dt < 4; ++dt) sOd[ri*128 + dt*32 + ln] = od[dt][r];
        }
        if (hi == 0) sl[ln] = lsum;
    }
    __syncthreads();
    if (ww == 0) {
        float inv = 1.0f / (lsum + sl[ln]);
        #pragma unroll
        for (int r = 0; r < 16; ++r) {
            int ri = (r & 3) + 8*(r >> 2) + 4*hi;
            float ivr = __shfl(inv, ri, 64);
            int row = q0 + ri;
            #pragma unroll
            for (int dt = 0; dt < 4; ++dt) {
                float v = (od[dt][r] + sOd[ri*128 + dt*32 + ln]) * ivr;
                y[((size_t)(b*CTX + row)) * (NH*HD) + h*HD + dt*32 + ln] = f2bf(v);
            }
        }
    }
}

// ---------- workspace layout (bytes) ----------
#define SIN_OFF   ((size_t)0)
#define XB_OFF    ((size_t)524288)
#define WT_OFF    ((size_t)17301504)
#define WOT_OFF   ((size_t)29884416)
#define QB_OFF    ((size_t)88604672)
#define KB_OFF    ((size_t)105381888)
#define VT_OFF    ((size_t)109576192)
#define YB_OFF    ((size_t)113770496)

extern "C" void kernel_launch(void* const* d_in, const int* in_sizes, int n_in,
                              void* d_out, int out_size, void* d_ws, size_t ws_size,
                              hipStream_t stream) {
    const float* x  = (const float*)d_in[0];
    const float* Wq = (const float*)d_in[1];
    const float* Wk = (const float*)d_in[2];
    const float* Wv = (const float*)d_in[3];
    const float* Wo = (const float*)d_in[4];
    const float* bo = (const float*)d_in[5];
    float* out = (float*)d_out;
    char* ws = (char*)d_ws;

    float*  sintab = (float*)(ws + SIN_OFF);
    ushort* xb     = (ushort*)(ws + XB_OFF);
    ushort* Wt     = (ushort*)(ws + WT_OFF);
    ushort* Wot    = (ushort*)(ws + WOT_OFF);
    ushort* Qf     = (ushort*)(ws + QB_OFF);
    ushort* Kf     = (ushort*)(ws + KB_OFF);
    ushort* Vf     = (ushort*)(ws + VT_OFF);
    ushort* yb     = (ushort*)(ws + YB_OFF);

    const float qscale = 0.08838834764831845f * 1.4426950408889634f;  // 1/sqrt(128) * log2(e)

    // 1. fused prep: sintab + x->bf16 + weight transposes
    k_prep<<<PREP_SIN + PREP_CVT + 4*4096, 256, 0, stream>>>(x, Wq, Wk, Wv, Wo, sintab, xb, Wt, Wot);
    // 2. QKV GEMM with fused RoPE + fragment-order epilogue -> Qf, Kf, Vf directly
    k_gemm_qkv<<<dim3(NQK/128, MROWS/128), 256, 0, stream>>>(xb, Wt, sintab, Qf, Kf, Vf, qscale);
    // 3. attention (512 blocks x 8 waves, Q in regs, KV double-buffered)
    k_attn15<<<512, 512, 0, stream>>>(Qf, Kf, Vf, yb);
    // 4. out = y @ Wo + bo  (f32 out)
    k_gemm_bt<<<dim3(EMB/128, MROWS/128), 256, 0, stream>>>(yb, Wot, out, MROWS, EMB, EMB, bo);
}